// Round 2
// baseline (2173.693 us; speedup 1.0000x reference)
//
#include <hip/hip_runtime.h>
#include <math.h>

#define N_OBS_C 2000000
#define N_REFL_C 250000
#define N_IMG_C 2000
#define MC_C 32
#define HID 64
#define LOG2PI_F 1.8378770664093453f

// ---------------- workspace layout (bytes) ----------------
// [0,8)        kl_sum   (double)
// [8,16)       llmax_sum(double)
// [16,64)      pearson sums: w, wx, wy, wxx, wyy, wxy (6 doubles)
// [64,16064)   img_ll [2000][2] float
// [16064,24064) op_idx [2000] int
// [32768, ...) sq      [250000] float
// [1048576,..) img_pre [2000][64] float   (b1 + emb-part of W1)
// [2097152,..) zT      [250000][32] float
// [34603008,.) ipred_mean [2000000][2] float

__device__ __forceinline__ float softplusf(float x) {
    return (x > 20.f) ? x : log1pf(expf(x));
}

// ---- K1: per-reflection: sq = softplus(q_scale_raw), KL partial, zT table ----
__global__ __launch_bounds__(256) void k_refl(const float* __restrict__ q_loc,
                                              const float* __restrict__ q_scale_raw,
                                              const float* __restrict__ zeps,
                                              float* __restrict__ sq,
                                              float* __restrict__ zT,
                                              double* __restrict__ kl_sum) {
    int r = blockIdx.x * 256 + threadIdx.x;
    double kl = 0.0;
    if (r < N_REFL_C) {
        float ql = q_loc[r];
        float sp = softplusf(q_scale_raw[r]);
        sq[r] = sp;
        kl = (double)(-logf(sp) + 0.5f * (sp * sp + ql * ql) - 0.5f);
        float z[MC_C];
#pragma unroll
        for (int m = 0; m < MC_C; ++m)
            z[m] = fmaf(sp, zeps[(size_t)m * N_REFL_C + r], ql);
        float4* outp = (float4*)(zT + (size_t)r * MC_C);
#pragma unroll
        for (int q = 0; q < MC_C / 4; ++q)
            outp[q] = make_float4(z[4 * q], z[4 * q + 1], z[4 * q + 2], z[4 * q + 3]);
    }
    for (int o = 32; o > 0; o >>= 1) kl += __shfl_xor(kl, o);
    __shared__ double skl[4];
    int lane = threadIdx.x & 63, w = threadIdx.x >> 6;
    if (lane == 0) skl[w] = kl;
    __syncthreads();
    if (threadIdx.x == 0) atomicAdd(kl_sum, skl[0] + skl[1] + skl[2] + skl[3]);
}

// ---- K1b: per-image precompute: img_pre[g][j] = b1[j] + sum_e emb[g][e]*W1[12+e][j] ----
__global__ __launch_bounds__(64) void k_imgpre(const float* __restrict__ img_emb,
                                               const float* __restrict__ W1,
                                               const float* __restrict__ b1,
                                               float* __restrict__ img_pre) {
    int g = blockIdx.x;
    int j = threadIdx.x;
    float acc = b1[j];
#pragma unroll
    for (int e = 0; e < 32; ++e)
        acc = fmaf(img_emb[g * 32 + e], W1[(12 + e) * HID + j], acc);
    img_pre[g * HID + j] = acc;
}

// ---- K2: main fused per-obs kernel ----
__global__ __launch_bounds__(256, 4) void k_main(const float* __restrict__ I,
                                              const float* __restrict__ SigI,
                                              const int* __restrict__ image_id,
                                              const float* __restrict__ metadata,
                                              const float* __restrict__ wavelength,
                                              const float* __restrict__ dHKL,
                                              const int* __restrict__ refl_ids,
                                              const float* __restrict__ q_loc,
                                              const float* __restrict__ W1,
                                              const float* __restrict__ W2,
                                              const float* __restrict__ b2,
                                              const float* __restrict__ seps,
                                              const float* __restrict__ sq,
                                              const float* __restrict__ img_pre,
                                              const float* __restrict__ zT,
                                              float* __restrict__ img_ll,
                                              float* __restrict__ ipred_mean) {
    __shared__ float sW1[12 * HID];   // rows 0..11 of W1 (Imodel2, Iscale2, meta8)
    __shared__ float sW2[HID * 2];
    __shared__ float sb2[2];
    for (int t = threadIdx.x; t < 12 * HID; t += 256) sW1[t] = W1[t];
    for (int t = threadIdx.x; t < HID * 2; t += 256) sW2[t] = W2[t];
    if (threadIdx.x < 2) sb2[threadIdx.x] = b2[threadIdx.x];
    __syncthreads();

    int n = blockIdx.x * 256 + threadIdx.x;
    bool active = (n < N_OBS_C);
    int nn = active ? n : (N_OBS_C - 1);

    float In = I[nn];
    float Sn = SigI[nn];
    float f[12];
    f[2] = In;
    f[3] = Sn;
#pragma unroll
    for (int i = 0; i < 6; ++i) f[4 + i] = metadata[(size_t)nn * 6 + i];
    f[10] = wavelength[nn];
    float dh = dHKL[nn];
    f[11] = 1.0f / (dh * dh);
    int g = image_id[nn];
    int rid0 = refl_ids[nn];
    int rid1 = refl_ids[N_OBS_C + nn];
    float qr0 = q_loc[rid0], sr0 = sq[rid0];
    float qr1 = q_loc[rid1], sr1 = sq[rid1];
    const float* ipg = img_pre + (size_t)g * HID;

    float l00 = sb2[0], l01 = sb2[1];   // loc_ls for op0
    float l10 = sb2[0], l11 = sb2[1];   // loc_ls for op1

#pragma unroll
    for (int jt = 0; jt < HID; jt += 8) {
        float accs[8];
#pragma unroll
        for (int jj = 0; jj < 8; ++jj) accs[jj] = ipg[jt + jj];
#pragma unroll
        for (int i = 2; i < 12; ++i) {
            float fi = f[i];
#pragma unroll
            for (int jj = 0; jj < 8; ++jj)
                accs[jj] = fmaf(fi, sW1[i * HID + jt + jj], accs[jj]);
        }
#pragma unroll
        for (int jj = 0; jj < 8; ++jj) {
            float w0 = sW1[jt + jj];
            float w1 = sW1[HID + jt + jj];
            float v2a = sW2[(jt + jj) * 2 + 0];
            float v2b = sW2[(jt + jj) * 2 + 1];
            float h0 = fmaf(qr0, w0, fmaf(sr0, w1, accs[jj]));
            h0 = fmaxf(h0, 0.f);
            l00 = fmaf(h0, v2a, l00);
            l01 = fmaf(h0, v2b, l01);
            float h1 = fmaf(qr1, w0, fmaf(sr1, w1, accs[jj]));
            h1 = fmaxf(h1, 0.f);
            l10 = fmaf(h1, v2a, l10);
            l11 = fmaf(h1, v2b, l11);
        }
    }

    float rsig = 1.0f / Sn;
    float mnIr = -In * rsig;
    float logS32 = 32.f * logf(Sn) + 16.f * LOG2PI_F;

    float sp0 = softplusf(l01);
    float sp1 = softplusf(l11);

    const float4* sep4 = (const float4*)(seps + (size_t)nn * MC_C);
    const float4* z40 = (const float4*)(zT + (size_t)rid0 * MC_C);
    const float4* z41 = (const float4*)(zT + (size_t)rid1 * MC_C);

    float sd20 = 0.f, sip0 = 0.f, sd21 = 0.f, sip1 = 0.f;
#pragma unroll 2
    for (int q = 0; q < 8; ++q) {
        float4 ss = sep4[q];
        float4 z0 = z40[q];
        float4 z1 = z41[q];
#define MCSTEP(zc0, zc1, sc_)                                  \
        {                                                      \
            float sc0 = fmaf(sp0, sc_, l00);                   \
            float ip0 = zc0 * sc0;                             \
            float d0 = fmaf(ip0, rsig, mnIr);                  \
            sd20 = fmaf(d0, d0, sd20);                         \
            sip0 += ip0;                                       \
            float sc1 = fmaf(sp1, sc_, l10);                   \
            float ip1 = zc1 * sc1;                             \
            float d1 = fmaf(ip1, rsig, mnIr);                  \
            sd21 = fmaf(d1, d1, sd21);                         \
            sip1 += ip1;                                       \
        }
        MCSTEP(z0.x, z1.x, ss.x)
        MCSTEP(z0.y, z1.y, ss.y)
        MCSTEP(z0.z, z1.z, ss.z)
        MCSTEP(z0.w, z1.w, ss.w)
#undef MCSTEP
    }

    float llo0 = -0.5f * sd20 - logS32;
    float llo1 = -0.5f * sd21 - logS32;

    if (active) {
        float2* ip2 = (float2*)(ipred_mean + (size_t)n * 2);
        *ip2 = make_float2(sip0 * (1.0f / 32.0f), sip1 * (1.0f / 32.0f));
    } else {
        llo0 = 0.f; llo1 = 0.f;
    }

    int gf = __shfl(g, 0);
    bool allsame = __all(g == gf);
    if (allsame) {
        for (int o = 32; o > 0; o >>= 1) {
            llo0 += __shfl_xor(llo0, o);
            llo1 += __shfl_xor(llo1, o);
        }
        if ((threadIdx.x & 63) == 0) {
            atomicAdd(&img_ll[gf * 2 + 0], llo0);
            atomicAdd(&img_ll[gf * 2 + 1], llo1);
        }
    } else if (active) {
        atomicAdd(&img_ll[g * 2 + 0], llo0);
        atomicAdd(&img_ll[g * 2 + 1], llo1);
    }
}

// ---- K3: per-image argmax + sum of ll_max ----
__global__ __launch_bounds__(256) void k_img(const float* __restrict__ img_ll,
                                             int* __restrict__ op_idx,
                                             double* __restrict__ llmax_sum) {
    int g = blockIdx.x * 256 + threadIdx.x;
    double v = 0.0;
    if (g < N_IMG_C) {
        float v0 = img_ll[g * 2 + 0] * (1.0f / 32.0f);
        float v1 = img_ll[g * 2 + 1] * (1.0f / 32.0f);
        op_idx[g] = (v1 > v0) ? 1 : 0;
        v = (double)fmaxf(v0, v1);
    }
    for (int o = 32; o > 0; o >>= 1) v += __shfl_xor(v, o);
    __shared__ double sv[4];
    int lane = threadIdx.x & 63, w = threadIdx.x >> 6;
    if (lane == 0) sv[w] = v;
    __syncthreads();
    if (threadIdx.x == 0) atomicAdd(llmax_sum, sv[0] + sv[1] + sv[2] + sv[3]);
}

// ---- K4: weighted pearson moment sums ----
__global__ __launch_bounds__(256) void k_pearson(const float* __restrict__ I,
                                                 const float* __restrict__ SigI,
                                                 const int* __restrict__ image_id,
                                                 const float* __restrict__ ipred_mean,
                                                 const int* __restrict__ op_idx,
                                                 double* __restrict__ acc) {
    int n = blockIdx.x * 256 + threadIdx.x;
    double s[6] = {0, 0, 0, 0, 0, 0};
    if (n < N_OBS_C) {
        float x = I[n];
        float sg = SigI[n];
        float w = 1.0f / (sg * sg);
        int g = image_id[n];
        int o = op_idx[g];
        float y = ipred_mean[(size_t)n * 2 + o];
        double dw = (double)w, dx = (double)x, dy = (double)y;
        s[0] = dw;
        s[1] = dw * dx;
        s[2] = dw * dy;
        s[3] = dw * dx * dx;
        s[4] = dw * dy * dy;
        s[5] = dw * dx * dy;
    }
#pragma unroll
    for (int k = 0; k < 6; ++k)
        for (int o = 32; o > 0; o >>= 1) s[k] += __shfl_xor(s[k], o);
    __shared__ double red[4][6];
    int lane = threadIdx.x & 63, w = threadIdx.x >> 6;
    if (lane == 0) {
#pragma unroll
        for (int k = 0; k < 6; ++k) red[w][k] = s[k];
    }
    __syncthreads();
    if (threadIdx.x < 6) {
        double t = red[0][threadIdx.x] + red[1][threadIdx.x] +
                   red[2][threadIdx.x] + red[3][threadIdx.x];
        atomicAdd(&acc[threadIdx.x], t);
    }
}

// ---- K5: finalize ----
__global__ void k_final(const double* __restrict__ accs, float* __restrict__ out) {
    double kl = accs[0] / (double)N_REFL_C;
    double elbo = -(accs[1] / (double)N_IMG_C) + 1.0 * kl;
    double W = accs[2], Sx = accs[3], Sy = accs[4];
    double Sxx = accs[5], Syy = accs[6], Sxy = accs[7];
    double z = 1.0 / W;
    double mx = z * Sx, my = z * Sy;
    double cxy = z * Sxy - mx * my;
    double cx = z * Sxx - mx * mx;
    double cy = z * Syy - my * my;
    double cc = cxy / sqrt(cx * cy);
    out[0] = (float)elbo;
    out[1] = (float)cc;
}

extern "C" void kernel_launch(void* const* d_in, const int* in_sizes, int n_in,
                              void* d_out, int out_size, void* d_ws, size_t ws_size,
                              hipStream_t stream) {
    const float* I = (const float*)d_in[0];
    const float* SigI = (const float*)d_in[1];
    const int* image_id = (const int*)d_in[2];
    const float* metadata = (const float*)d_in[3];
    const float* wavelength = (const float*)d_in[4];
    const float* dHKL = (const float*)d_in[5];
    const int* refl_ids = (const int*)d_in[6];
    const float* q_loc = (const float*)d_in[7];
    const float* q_scale_raw = (const float*)d_in[8];
    const float* img_emb = (const float*)d_in[9];
    const float* W1 = (const float*)d_in[10];
    const float* b1 = (const float*)d_in[11];
    const float* W2 = (const float*)d_in[12];
    const float* b2 = (const float*)d_in[13];
    const float* zeps = (const float*)d_in[14];
    const float* seps = (const float*)d_in[15];
    float* out = (float*)d_out;

    char* ws = (char*)d_ws;
    double* accs = (double*)ws;                    // [0]=kl [1]=llmax [2..7]=pearson
    float* img_ll = (float*)(ws + 64);             // [2000][2]
    int* op_idx = (int*)(ws + 16064);              // [2000]
    float* sqv = (float*)(ws + 32768);             // [250000]
    float* img_pre = (float*)(ws + 1048576);       // [2000][64]
    float* zT = (float*)(ws + 2097152);            // [250000][32]
    float* ipred = (float*)(ws + 34603008);        // [2000000][2]

    hipMemsetAsync(d_ws, 0, 16064, stream);

    k_refl<<<(N_REFL_C + 255) / 256, 256, 0, stream>>>(q_loc, q_scale_raw, zeps,
                                                       sqv, zT, &accs[0]);
    k_imgpre<<<N_IMG_C, 64, 0, stream>>>(img_emb, W1, b1, img_pre);
    k_main<<<(N_OBS_C + 255) / 256, 256, 0, stream>>>(I, SigI, image_id, metadata,
                                                      wavelength, dHKL, refl_ids,
                                                      q_loc, W1, W2, b2, seps, sqv,
                                                      img_pre, zT, img_ll, ipred);
    k_img<<<(N_IMG_C + 255) / 256, 256, 0, stream>>>(img_ll, op_idx, &accs[1]);
    k_pearson<<<(N_OBS_C + 255) / 256, 256, 0, stream>>>(I, SigI, image_id, ipred,
                                                         op_idx, &accs[2]);
    k_final<<<1, 1, 0, stream>>>(accs, out);
}

// Round 3
// 599.607 us; speedup vs baseline: 3.6252x; 3.6252x over previous
//
#include <hip/hip_runtime.h>
#include <math.h>

#define N_OBS_C 2000000
#define N_REFL_C 250000
#define N_IMG_C 2000
#define MC_C 32
#define HID 64
#define LOG2PI_F 1.8378770664093453f

// ---------------- workspace layout (bytes) ----------------
// [0,8)        kl_sum   (double)
// [8,16)       llmax_sum(double)
// [16,64)      pearson sums: w, wx, wy, wxx, wyy, wxy (6 doubles)
// [64,16064)   img_ll [2000][2] float
// [16064,24064) op_idx [2000] int
// [32768, ...) sq      [250000] float
// [1048576,..) img_pre [2000][64] float   (b1 + emb-part of W1)
// [2097152,..) zT      [250000][32] float
// [34603008,.) ipred_mean [2000000][2] float
// [52428800,.) params  [2000000] float4 (loc0, sp0, loc1, sp1)  (32 MB)

__device__ __forceinline__ float softplusf(float x) {
    return (x > 20.f) ? x : log1pf(expf(x));
}

// ---- K1: per-reflection: sq = softplus(q_scale_raw), KL partial, zT table ----
__global__ __launch_bounds__(256) void k_refl(const float* __restrict__ q_loc,
                                              const float* __restrict__ q_scale_raw,
                                              const float* __restrict__ zeps,
                                              float* __restrict__ sq,
                                              float* __restrict__ zT,
                                              double* __restrict__ kl_sum) {
    int r = blockIdx.x * 256 + threadIdx.x;
    double kl = 0.0;
    if (r < N_REFL_C) {
        float ql = q_loc[r];
        float sp = softplusf(q_scale_raw[r]);
        sq[r] = sp;
        kl = (double)(-logf(sp) + 0.5f * (sp * sp + ql * ql) - 0.5f);
        float z[MC_C];
#pragma unroll
        for (int m = 0; m < MC_C; ++m)
            z[m] = fmaf(sp, zeps[(size_t)m * N_REFL_C + r], ql);
        float4* outp = (float4*)(zT + (size_t)r * MC_C);
#pragma unroll
        for (int q = 0; q < MC_C / 4; ++q)
            outp[q] = make_float4(z[4 * q], z[4 * q + 1], z[4 * q + 2], z[4 * q + 3]);
    }
    for (int o = 32; o > 0; o >>= 1) kl += __shfl_xor(kl, o);
    __shared__ double skl[4];
    int lane = threadIdx.x & 63, w = threadIdx.x >> 6;
    if (lane == 0) skl[w] = kl;
    __syncthreads();
    if (threadIdx.x == 0) atomicAdd(kl_sum, skl[0] + skl[1] + skl[2] + skl[3]);
}

// ---- K1b: per-image precompute: img_pre[g][j] = b1[j] + sum_e emb[g][e]*W1[12+e][j] ----
__global__ __launch_bounds__(64) void k_imgpre(const float* __restrict__ img_emb,
                                               const float* __restrict__ W1,
                                               const float* __restrict__ b1,
                                               float* __restrict__ img_pre) {
    int g = blockIdx.x;
    int j = threadIdx.x;
    float acc = b1[j];
#pragma unroll
    for (int e = 0; e < 32; ++e)
        acc = fmaf(img_emb[g * 32 + e], W1[(12 + e) * HID + j], acc);
    img_pre[g * HID + j] = acc;
}

// ---- K2a: MLP per obs -> params (loc0, sp0, loc1, sp1) ----
__global__ __launch_bounds__(256) void k_mlp(const float* __restrict__ I,
                                             const float* __restrict__ SigI,
                                             const int* __restrict__ image_id,
                                             const float* __restrict__ metadata,
                                             const float* __restrict__ wavelength,
                                             const float* __restrict__ dHKL,
                                             const int* __restrict__ refl_ids,
                                             const float* __restrict__ q_loc,
                                             const float* __restrict__ W1,
                                             const float* __restrict__ W2,
                                             const float* __restrict__ b2,
                                             const float* __restrict__ sq,
                                             const float* __restrict__ img_pre,
                                             float4* __restrict__ params) {
    int n = blockIdx.x * 256 + threadIdx.x;
    bool active = (n < N_OBS_C);
    int nn = active ? n : (N_OBS_C - 1);

    float f[12];
    f[2] = I[nn];
    f[3] = SigI[nn];
#pragma unroll
    for (int i = 0; i < 6; ++i) f[4 + i] = metadata[(size_t)nn * 6 + i];
    f[10] = wavelength[nn];
    float dh = dHKL[nn];
    f[11] = 1.0f / (dh * dh);
    int g = image_id[nn];
    int rid0 = refl_ids[nn];
    int rid1 = refl_ids[N_OBS_C + nn];
    float qr0 = q_loc[rid0], sr0 = sq[rid0];
    float qr1 = q_loc[rid1], sr1 = sq[rid1];
    const float* ipg = img_pre + (size_t)g * HID;

    // b2 is wave-uniform -> scalar loads
    float l00 = b2[0], l01 = b2[1];
    float l10 = l00, l11 = l01;

#pragma unroll 1
    for (int jt = 0; jt < HID; jt += 8) {
        float accs[8];
#pragma unroll
        for (int jj = 0; jj < 8; ++jj) accs[jj] = ipg[jt + jj];
#pragma unroll
        for (int i = 2; i < 12; ++i) {
            float fi = f[i];
#pragma unroll
            for (int jj = 0; jj < 8; ++jj)
                accs[jj] = fmaf(fi, W1[i * HID + jt + jj], accs[jj]);
        }
#pragma unroll
        for (int jj = 0; jj < 8; ++jj) {
            float w0 = W1[jt + jj];          // W1 row 0 (q_loc)
            float w1 = W1[HID + jt + jj];    // W1 row 1 (sq)
            float v2a = W2[(jt + jj) * 2 + 0];
            float v2b = W2[(jt + jj) * 2 + 1];
            float h0 = fmaf(qr0, w0, fmaf(sr0, w1, accs[jj]));
            h0 = fmaxf(h0, 0.f);
            l00 = fmaf(h0, v2a, l00);
            l01 = fmaf(h0, v2b, l01);
            float h1 = fmaf(qr1, w0, fmaf(sr1, w1, accs[jj]));
            h1 = fmaxf(h1, 0.f);
            l10 = fmaf(h1, v2a, l10);
            l11 = fmaf(h1, v2b, l11);
        }
    }

    if (active)
        params[n] = make_float4(l00, softplusf(l01), l10, softplusf(l11));
}

// ---- K2b: MC likelihood + ipred ----
__global__ __launch_bounds__(256) void k_mc(const float* __restrict__ I,
                                            const float* __restrict__ SigI,
                                            const int* __restrict__ image_id,
                                            const int* __restrict__ refl_ids,
                                            const float4* __restrict__ params,
                                            const float* __restrict__ seps,
                                            const float* __restrict__ zT,
                                            float* __restrict__ img_ll,
                                            float* __restrict__ ipred_mean) {
    int n = blockIdx.x * 256 + threadIdx.x;
    bool active = (n < N_OBS_C);
    int nn = active ? n : (N_OBS_C - 1);

    float In = I[nn];
    float Sn = SigI[nn];
    int g = image_id[nn];
    int rid0 = refl_ids[nn];
    int rid1 = refl_ids[N_OBS_C + nn];
    float4 pp = params[nn];

    float rsig = 1.0f / Sn;
    float mnIr = -In * rsig;
    float logS32 = 32.f * logf(Sn) + 16.f * LOG2PI_F;

    const float4* sep4 = (const float4*)(seps + (size_t)nn * MC_C);
    const float4* z40 = (const float4*)(zT + (size_t)rid0 * MC_C);
    const float4* z41 = (const float4*)(zT + (size_t)rid1 * MC_C);

    float sd20 = 0.f, sip0 = 0.f, sd21 = 0.f, sip1 = 0.f;
#pragma unroll 2
    for (int q = 0; q < 8; ++q) {
        float4 ss = sep4[q];
        float4 z0 = z40[q];
        float4 z1 = z41[q];
#define MCSTEP(zc0, zc1, sc_)                                  \
        {                                                      \
            float sc0 = fmaf(pp.y, sc_, pp.x);                 \
            float ip0 = zc0 * sc0;                             \
            float d0 = fmaf(ip0, rsig, mnIr);                  \
            sd20 = fmaf(d0, d0, sd20);                         \
            sip0 += ip0;                                       \
            float sc1 = fmaf(pp.w, sc_, pp.z);                 \
            float ip1 = zc1 * sc1;                             \
            float d1 = fmaf(ip1, rsig, mnIr);                  \
            sd21 = fmaf(d1, d1, sd21);                         \
            sip1 += ip1;                                       \
        }
        MCSTEP(z0.x, z1.x, ss.x)
        MCSTEP(z0.y, z1.y, ss.y)
        MCSTEP(z0.z, z1.z, ss.z)
        MCSTEP(z0.w, z1.w, ss.w)
#undef MCSTEP
    }

    float llo0 = -0.5f * sd20 - logS32;
    float llo1 = -0.5f * sd21 - logS32;

    if (active) {
        float2* ip2 = (float2*)(ipred_mean + (size_t)n * 2);
        *ip2 = make_float2(sip0 * (1.0f / 32.0f), sip1 * (1.0f / 32.0f));
    } else {
        llo0 = 0.f; llo1 = 0.f;
    }

    int gf = __shfl(g, 0);
    bool allsame = __all(g == gf);
    if (allsame) {
        for (int o = 32; o > 0; o >>= 1) {
            llo0 += __shfl_xor(llo0, o);
            llo1 += __shfl_xor(llo1, o);
        }
        if ((threadIdx.x & 63) == 0) {
            atomicAdd(&img_ll[gf * 2 + 0], llo0);
            atomicAdd(&img_ll[gf * 2 + 1], llo1);
        }
    } else if (active) {
        atomicAdd(&img_ll[g * 2 + 0], llo0);
        atomicAdd(&img_ll[g * 2 + 1], llo1);
    }
}

// ---- K3: per-image argmax + sum of ll_max ----
__global__ __launch_bounds__(256) void k_img(const float* __restrict__ img_ll,
                                             int* __restrict__ op_idx,
                                             double* __restrict__ llmax_sum) {
    int g = blockIdx.x * 256 + threadIdx.x;
    double v = 0.0;
    if (g < N_IMG_C) {
        float v0 = img_ll[g * 2 + 0] * (1.0f / 32.0f);
        float v1 = img_ll[g * 2 + 1] * (1.0f / 32.0f);
        op_idx[g] = (v1 > v0) ? 1 : 0;
        v = (double)fmaxf(v0, v1);
    }
    for (int o = 32; o > 0; o >>= 1) v += __shfl_xor(v, o);
    __shared__ double sv[4];
    int lane = threadIdx.x & 63, w = threadIdx.x >> 6;
    if (lane == 0) sv[w] = v;
    __syncthreads();
    if (threadIdx.x == 0) atomicAdd(llmax_sum, sv[0] + sv[1] + sv[2] + sv[3]);
}

// ---- K4: weighted pearson moment sums ----
__global__ __launch_bounds__(256) void k_pearson(const float* __restrict__ I,
                                                 const float* __restrict__ SigI,
                                                 const int* __restrict__ image_id,
                                                 const float* __restrict__ ipred_mean,
                                                 const int* __restrict__ op_idx,
                                                 double* __restrict__ acc) {
    int n = blockIdx.x * 256 + threadIdx.x;
    double s[6] = {0, 0, 0, 0, 0, 0};
    if (n < N_OBS_C) {
        float x = I[n];
        float sg = SigI[n];
        float w = 1.0f / (sg * sg);
        int g = image_id[n];
        int o = op_idx[g];
        float y = ipred_mean[(size_t)n * 2 + o];
        double dw = (double)w, dx = (double)x, dy = (double)y;
        s[0] = dw;
        s[1] = dw * dx;
        s[2] = dw * dy;
        s[3] = dw * dx * dx;
        s[4] = dw * dy * dy;
        s[5] = dw * dx * dy;
    }
#pragma unroll
    for (int k = 0; k < 6; ++k)
        for (int o = 32; o > 0; o >>= 1) s[k] += __shfl_xor(s[k], o);
    __shared__ double red[4][6];
    int lane = threadIdx.x & 63, w = threadIdx.x >> 6;
    if (lane == 0) {
#pragma unroll
        for (int k = 0; k < 6; ++k) red[w][k] = s[k];
    }
    __syncthreads();
    if (threadIdx.x < 6) {
        double t = red[0][threadIdx.x] + red[1][threadIdx.x] +
                   red[2][threadIdx.x] + red[3][threadIdx.x];
        atomicAdd(&acc[threadIdx.x], t);
    }
}

// ---- K5: finalize ----
__global__ void k_final(const double* __restrict__ accs, float* __restrict__ out) {
    double kl = accs[0] / (double)N_REFL_C;
    double elbo = -(accs[1] / (double)N_IMG_C) + 1.0 * kl;
    double W = accs[2], Sx = accs[3], Sy = accs[4];
    double Sxx = accs[5], Syy = accs[6], Sxy = accs[7];
    double z = 1.0 / W;
    double mx = z * Sx, my = z * Sy;
    double cxy = z * Sxy - mx * my;
    double cx = z * Sxx - mx * mx;
    double cy = z * Syy - my * my;
    double cc = cxy / sqrt(cx * cy);
    out[0] = (float)elbo;
    out[1] = (float)cc;
}

extern "C" void kernel_launch(void* const* d_in, const int* in_sizes, int n_in,
                              void* d_out, int out_size, void* d_ws, size_t ws_size,
                              hipStream_t stream) {
    const float* I = (const float*)d_in[0];
    const float* SigI = (const float*)d_in[1];
    const int* image_id = (const int*)d_in[2];
    const float* metadata = (const float*)d_in[3];
    const float* wavelength = (const float*)d_in[4];
    const float* dHKL = (const float*)d_in[5];
    const int* refl_ids = (const int*)d_in[6];
    const float* q_loc = (const float*)d_in[7];
    const float* q_scale_raw = (const float*)d_in[8];
    const float* img_emb = (const float*)d_in[9];
    const float* W1 = (const float*)d_in[10];
    const float* b1 = (const float*)d_in[11];
    const float* W2 = (const float*)d_in[12];
    const float* b2 = (const float*)d_in[13];
    const float* zeps = (const float*)d_in[14];
    const float* seps = (const float*)d_in[15];
    float* out = (float*)d_out;

    char* ws = (char*)d_ws;
    double* accs = (double*)ws;                    // [0]=kl [1]=llmax [2..7]=pearson
    float* img_ll = (float*)(ws + 64);             // [2000][2]
    int* op_idx = (int*)(ws + 16064);              // [2000]
    float* sqv = (float*)(ws + 32768);             // [250000]
    float* img_pre = (float*)(ws + 1048576);       // [2000][64]
    float* zT = (float*)(ws + 2097152);            // [250000][32]
    float* ipred = (float*)(ws + 34603008);        // [2000000][2]
    float4* params = (float4*)(ws + 52428800);     // [2000000] float4

    hipMemsetAsync(d_ws, 0, 16064, stream);

    k_refl<<<(N_REFL_C + 255) / 256, 256, 0, stream>>>(q_loc, q_scale_raw, zeps,
                                                       sqv, zT, &accs[0]);
    k_imgpre<<<N_IMG_C, 64, 0, stream>>>(img_emb, W1, b1, img_pre);
    k_mlp<<<(N_OBS_C + 255) / 256, 256, 0, stream>>>(I, SigI, image_id, metadata,
                                                     wavelength, dHKL, refl_ids,
                                                     q_loc, W1, W2, b2, sqv,
                                                     img_pre, params);
    k_mc<<<(N_OBS_C + 255) / 256, 256, 0, stream>>>(I, SigI, image_id, refl_ids,
                                                    params, seps, zT, img_ll, ipred);
    k_img<<<(N_IMG_C + 255) / 256, 256, 0, stream>>>(img_ll, op_idx, &accs[1]);
    k_pearson<<<(N_OBS_C + 255) / 256, 256, 0, stream>>>(I, SigI, image_id, ipred,
                                                         op_idx, &accs[2]);
    k_final<<<1, 1, 0, stream>>>(accs, out);
}